// Round 9
// baseline (2378.522 us; speedup 1.0000x reference)
//
#include <hip/hip_runtime.h>

typedef __attribute__((ext_vector_type(8))) short short8;
typedef __attribute__((ext_vector_type(4))) float f32x4;

#define SEQ_BLOCKS 64

__device__ __forceinline__ unsigned short f2bf(float f) {
  unsigned u = __float_as_uint(f);
  u = u + 0x7fffu + ((u >> 16) & 1u);
  return (unsigned short)(u >> 16);
}
__device__ __forceinline__ unsigned short f2h(float f) {
  _Float16 h = (_Float16)f;
  unsigned short r;
  __builtin_memcpy(&r, &h, 2);
  return r;
}
__device__ __forceinline__ float h2f(unsigned short u) {
  _Float16 h;
  __builtin_memcpy(&h, &u, 2);
  return (float)h;
}
__device__ __forceinline__ void gload16(const void* g, void* l) {
  __builtin_amdgcn_global_load_lds(
      (const __attribute__((address_space(1))) unsigned int*)g,
      (__attribute__((address_space(3))) unsigned int*)l, 16, 0, 0);
}
__device__ __forceinline__ float fast_sigmoid(float x) {
  return 1.0f / (1.0f + __expf(-x));
}
__device__ __forceinline__ float fast_tanh(float x) {
  return 2.0f / (1.0f + __expf(-2.0f * x)) - 1.0f;
}
// L2-bypassing (sc0 sc1) atomics for cross-XCD exchange through L3
__device__ __forceinline__ unsigned long long ld_u64(const unsigned long long* p) {
  return __hip_atomic_load(p, __ATOMIC_RELAXED, __HIP_MEMORY_SCOPE_AGENT);
}
__device__ __forceinline__ void st_u64(unsigned long long* p, unsigned long long v) {
  __hip_atomic_store(p, v, __ATOMIC_RELAXED, __HIP_MEMORY_SCOPE_AGENT);
}

// ---------- elementwise fp32 -> bf16 convert (vectorized) ----------
__global__ void k_conv_bf16(const float* __restrict__ in, unsigned short* __restrict__ out) {
  size_t i = ((size_t)blockIdx.x * 256 + threadIdx.x) * 4;
  float4 v = *(const float4*)(in + i);
  unsigned short o[4] = {f2bf(v.x), f2bf(v.y), f2bf(v.z), f2bf(v.w)};
  *(uint2*)(out + i) = *(const uint2*)o;
}

// ---------- h0 into slot 0: hstep[0][sb][row][16] ----------
__global__ void k_h0t(const float* __restrict__ hidden, unsigned short* __restrict__ hT) {
  int sb = blockIdx.x;
  int row = threadIdx.x >> 2, c4 = (threadIdx.x & 3) * 4;
  float4 v = *(const float4*)(hidden + (size_t)row * 1024 + sb * 16 + c4);
  unsigned short o[4] = {f2bf(v.x), f2bf(v.y), f2bf(v.z), f2bf(v.w)};
  unsigned long long u;
  __builtin_memcpy(&u, o, 8);
  *(unsigned long long*)(hT + (size_t)sb * 1024 + row * 16 + c4) = u;
}

// ---------- transpose + convert: out[c][r] = bf16(in[r][c]) ----------
__global__ void k_transpose(const float* __restrict__ in, unsigned short* __restrict__ out,
                            int R, int C) {
  __shared__ float tile[32][33];
  int bx = blockIdx.x * 32, by = blockIdx.y * 32;
  int tx = threadIdx.x & 31, ty = threadIdx.x >> 5;  // ty 0..7
  for (int i = 0; i < 32; i += 8)
    tile[ty + i][tx] = in[(size_t)(by + ty + i) * C + bx + tx];
  __syncthreads();
  for (int i = 0; i < 32; i += 8)
    out[(size_t)(bx + ty + i) * R + by + tx] = f2bf(tile[tx][ty + i]);
}

// ---------- generic bf16 GEMM, C = A @ B^T (+bias), A[M][K], B[N][K] bf16 ----------
// OUTMODE 0: bf16 linear C[row][col]
// OUTMODE 1: fp16 tiled GX2[t][blk][g][b][jj]  (row = t*64+b, col = g*1024 + blk*16 + jj)
template<int OUTMODE>
__global__ __launch_bounds__(256) void k_gemm_bt(
    const unsigned short* __restrict__ A, const unsigned short* __restrict__ B,
    unsigned short* __restrict__ C, const float* __restrict__ bias,
    int M, int N, int K) {
  __shared__ unsigned short As[128 * 32];
  __shared__ unsigned short Bs[128 * 32];
  const int tid = threadIdx.x;
  const int wv = tid >> 6, l = tid & 63;
  const int m0 = blockIdx.y * 128, n0 = blockIdx.x * 128;
  const int wr = (wv >> 1) * 64, wc = (wv & 1) * 64;
  f32x4 acc[4][4] = {};
  for (int k0 = 0; k0 < K; k0 += 32) {
#pragma unroll
    for (int j = 0; j < 2; ++j) {
      int c = wv * 128 + j * 64 + l;
      int row = c >> 2, kc = (c & 3) * 8;
      gload16(A + (size_t)(m0 + row) * K + k0 + kc, (char*)As + c * 16);
      gload16(B + (size_t)(n0 + row) * K + k0 + kc, (char*)Bs + c * 16);
    }
    __syncthreads();
    short8 af[4], bfr[4];
#pragma unroll
    for (int rf = 0; rf < 4; ++rf)
      af[rf] = *(const short8*)(As + (wr + rf * 16 + (l & 15)) * 32 + (l >> 4) * 8);
#pragma unroll
    for (int cf = 0; cf < 4; ++cf)
      bfr[cf] = *(const short8*)(Bs + (wc + cf * 16 + (l & 15)) * 32 + (l >> 4) * 8);
#pragma unroll
    for (int rf = 0; rf < 4; ++rf)
#pragma unroll
      for (int cf = 0; cf < 4; ++cf)
        acc[rf][cf] = __builtin_amdgcn_mfma_f32_16x16x32_bf16(af[rf], bfr[cf], acc[rf][cf], 0, 0, 0);
    __syncthreads();
  }
#pragma unroll
  for (int cf = 0; cf < 4; ++cf) {
    int col = n0 + wc + cf * 16 + (l & 15);
    float bv = bias ? bias[col] : 0.0f;
#pragma unroll
    for (int rf = 0; rf < 4; ++rf) {
#pragma unroll
      for (int i = 0; i < 4; ++i) {
        int row = m0 + wr + rf * 16 + (l >> 4) * 4 + i;
        float v = acc[rf][cf][i] + bv;
        if (OUTMODE == 0) {
          C[(size_t)row * N + col] = f2bf(v);
        } else {
          int t = row >> 6, b = row & 63;
          int g = col >> 10, c = col & 1023;
          size_t idx = (size_t)(t * 64 + (c >> 4)) * 4096 + (g * 64 + b) * 16 + (c & 15);
          C[idx] = f2h(v);
        }
      }
    }
  }
}

// ---------- combined bias ----------
__global__ void k_bias(const float* __restrict__ Wxg, const float* __restrict__ bxg,
                       const float* __restrict__ b_in, const float* __restrict__ Whg,
                       const float* __restrict__ bhg, const float* __restrict__ b_hid,
                       float* __restrict__ gbias) {
  int col = blockIdx.x * 64 + (threadIdx.x >> 2);
  int p = threadIdx.x & 3;
  const float* wx = Wxg + (size_t)col * 1024;
  const float* wh = Whg + (size_t)col * 1024;
  float s = 0.f;
  for (int k = p * 256; k < p * 256 + 256; ++k)
    s += wx[k] * b_in[k] + wh[k] * b_hid[k];
  s += __shfl_down(s, 2, 4);
  s += __shfl_down(s, 1, 4);
  if (p == 0) gbias[col] = s + bxg[col] + bhg[col];
}

// ---------- persistent sequential LSTM scan (one-hop sentinel exchange) ----------
// 64 blocks x 4 waves. Block owns h-cols [bid*16,+16); wave wv owns k-quarter.
// hstep[257 slots][64 src][64 row][16 col] bf16 — each step has its OWN slot,
// pre-poisoned to 0xFF..F. Producer: pack 4xbf16 -> ONE u64 sc0/sc1 store,
// fire-and-forget (no drain, no tag, no barrier). Consumer: issue all 64 u64
// A-loads speculatively; selectively re-load words still == POISON (4 bf16
// tanh outputs can never be 4 NaNs). Critical path = ONE fabric hop + compute.
__global__ __launch_bounds__(256, 1) void k_lstm_seq(
    const unsigned short* __restrict__ GX2,  // fp16 tiled [256][64][4][64][16]
    const unsigned short* __restrict__ Whc,  // bf16 [4096][1024]
    const float* __restrict__ cell,          // [64][1024] f32
    unsigned short* __restrict__ hstep,      // bf16 [257][64][64][16], poisoned
    float* __restrict__ out) {               // h [64][1024], c [64][1024] f32
  __shared__ float pbuf[34816];              // 139 KB: (t&1)*17408 + s*4352 + gc*68 + b
  const int tid = threadIdx.x;
  const int wv = tid >> 6, l = tid & 63;
  const int bid = blockIdx.x;
  const int a = l & 15, q = l >> 4;
  const unsigned long long POISON = ~0ULL;

  // ---- weights: w[ct][u] = gate ct, h-col a of block; k = wv*256+u*32+q*8 ----
  short8 w[4][8];
#pragma unroll
  for (int ct = 0; ct < 4; ++ct)
#pragma unroll
    for (int u = 0; u < 8; ++u)
      w[ct][u] = *(const short8*)(
          Whc + (size_t)(ct * 1024 + bid * 16 + a) * 1024 + wv * 256 + u * 32 + q * 8);

  // elementwise ownership: batch-row eb, h-cols ej..ej+3
  const int eb = tid >> 2;
  const int ej = (tid & 3) * 4;
  float c_reg[4];
  {
    float4 c4 = *(const float4*)(cell + (size_t)eb * 1024 + bid * 16 + ej);
    c_reg[0] = c4.x; c_reg[1] = c4.y; c_reg[2] = c4.z; c_reg[3] = c4.w;
  }

  // A-load base inside a slot: src = wv*16 + 2u + (q>>1), row a, col8 = (q&1)*8
  const size_t abase = (size_t)(wv * 16 + (q >> 1)) * 1024 + a * 16 + (q & 1) * 8;

  for (int t = 0; t < 256; ++t) {
    // --- GX prefetch for this thread's outputs (plain loads) ---
    const unsigned short* chunk = GX2 + ((size_t)t * 64 + bid) * 4096;
    unsigned long long gxu[4];
#pragma unroll
    for (int g = 0; g < 4; ++g)
      gxu[g] = *(const unsigned long long*)(chunk + (g * 64 + eb) * 16 + ej);

    // --- speculative A-load from slot t + sentinel validation ---
    const unsigned short* hb = hstep + ((size_t)t << 16) + abase;
    unsigned long long ck[8][4][2];
#pragma unroll
    for (int u = 0; u < 8; ++u)
#pragma unroll
      for (int rt = 0; rt < 4; ++rt) {
        const unsigned long long* p = (const unsigned long long*)(hb + u * 2048 + rt * 256);
        ck[u][rt][0] = ld_u64(p);
        ck[u][rt][1] = ld_u64(p + 1);
      }
    for (;;) {
      unsigned nbad = 0;
#pragma unroll
      for (int u = 0; u < 8; ++u)
#pragma unroll
        for (int rt = 0; rt < 4; ++rt)
          nbad += (ck[u][rt][0] == POISON) + (ck[u][rt][1] == POISON);
      if (!__any((int)nbad)) break;
      __builtin_amdgcn_s_sleep(1);
#pragma unroll
      for (int u = 0; u < 8; ++u)
#pragma unroll
        for (int rt = 0; rt < 4; ++rt) {
          const unsigned long long* p = (const unsigned long long*)(hb + u * 2048 + rt * 256);
          if (ck[u][rt][0] == POISON) ck[u][rt][0] = ld_u64(p);
          if (ck[u][rt][1] == POISON) ck[u][rt][1] = ld_u64(p + 1);
        }
    }

    // --- 128 MFMA; fragments are the validated u64 pairs ---
    f32x4 acc[4][4] = {};
#pragma unroll
    for (int u = 0; u < 8; ++u)
#pragma unroll
      for (int rt = 0; rt < 4; ++rt) {
        union { unsigned long long d[2]; short8 s; } fb;
        fb.d[0] = ck[u][rt][0];
        fb.d[1] = ck[u][rt][1];
#pragma unroll
        for (int ct = 0; ct < 4; ++ct)
          acc[rt][ct] = __builtin_amdgcn_mfma_f32_16x16x32_bf16(fb.s, w[ct][u],
                                                                acc[rt][ct], 0, 0, 0);
      }

    // --- partials to LDS (R7-verified 0-conflict): f32x4 over batch ---
    const int pb = (t & 1) * 17408 + wv * 4352;
#pragma unroll
    for (int rt = 0; rt < 4; ++rt)
#pragma unroll
      for (int ct = 0; ct < 4; ++ct) {
        int gc = a * 4 + ct;                              // h-col-major gate-col
        int b0 = (rt * 16 + q * 4) ^ ((((gc) >> 3) & 3) << 2);
        *(f32x4*)&pbuf[pb + gc * 68 + b0] = acc[rt][ct];
      }
    __syncthreads();

    // --- reduce 4 k-slots + GX, gates for (row eb, cols ej..ej+3) ---
    const int pr = (t & 1) * 17408;
    float sg[4][4];
#pragma unroll
    for (int g = 0; g < 4; ++g) {
      unsigned short gx4[4];
      __builtin_memcpy(gx4, &gxu[g], 8);
#pragma unroll
      for (int i = 0; i < 4; ++i) {
        int gc = (ej + i) * 4 + g;
        int bx = eb ^ ((((gc) >> 3) & 3) << 2);
        float s = pbuf[pr + 0 * 4352 + gc * 68 + bx] + pbuf[pr + 1 * 4352 + gc * 68 + bx] +
                  pbuf[pr + 2 * 4352 + gc * 68 + bx] + pbuf[pr + 3 * 4352 + gc * 68 + bx];
        sg[g][i] = s + h2f(gx4[i]);
      }
    }
    float hnew[4];
#pragma unroll
    for (int i = 0; i < 4; ++i) {
      float ig = fast_sigmoid(sg[0][i]);
      float fg = fast_sigmoid(sg[1][i]);
      float gg = fast_tanh(sg[2][i]);
      float og = fast_sigmoid(sg[3][i]);
      c_reg[i] = fg * c_reg[i] + ig * gg;
      hnew[i] = og * fast_tanh(c_reg[i]);
    }

    if (t == 255) {
      float4 h4 = {hnew[0], hnew[1], hnew[2], hnew[3]};
      float4 c4 = {c_reg[0], c_reg[1], c_reg[2], c_reg[3]};
      *(float4*)(out + (size_t)eb * 1024 + bid * 16 + ej) = h4;
      *(float4*)(out + 65536 + (size_t)eb * 1024 + bid * 16 + ej) = c4;
    } else {
      // fire-and-forget h(t+1): ONE packed u64 store into slot t+1
      unsigned short hs[4] = {f2bf(hnew[0]), f2bf(hnew[1]), f2bf(hnew[2]), f2bf(hnew[3])};
      unsigned long long hv;
      __builtin_memcpy(&hv, hs, 8);
      st_u64((unsigned long long*)(hstep + ((size_t)(t + 1) << 16) + (size_t)bid * 1024 +
                                   eb * 16 + ej),
             hv);
    }
  }
}

extern "C" void kernel_launch(void* const* d_in, const int* in_sizes, int n_in,
                              void* d_out, int out_size, void* d_ws, size_t ws_size,
                              hipStream_t stream) {
  const float* x      = (const float*)d_in[0];
  const float* hidden = (const float*)d_in[1];
  const float* cell   = (const float*)d_in[2];
  const float* W_in   = (const float*)d_in[3];
  const float* b_in   = (const float*)d_in[4];
  const float* W_hid  = (const float*)d_in[5];
  const float* b_hid  = (const float*)d_in[6];
  const float* Wx_g   = (const float*)d_in[7];
  const float* bx_g   = (const float*)d_in[8];
  const float* Wh_g   = (const float*)d_in[9];
  const float* bh_g   = (const float*)d_in[10];
  float* out = (float*)d_out;

  char* ws = (char*)d_ws;
  unsigned short* GX2   = (unsigned short*)(ws);                 // 134217728 B (fp16 tiled)
  unsigned short* Xbf   = (unsigned short*)(ws + 134217728);     // 33554432 (freed after GX gemm)
  unsigned short* WxGb  = (unsigned short*)(ws + 167772160);     // 8388608 (freed after Wxc gemm)
  unsigned short* WhGb  = (unsigned short*)(ws + 176160768);     // 8388608
  unsigned short* WinT  = (unsigned short*)(ws + 184549376);     // 2097152
  unsigned short* WhidT = (unsigned short*)(ws + 186646528);     // 2097152
  unsigned short* Wxc   = (unsigned short*)(ws + 188743680);     // 8388608
  unsigned short* Whc   = (unsigned short*)(ws + 197132288);     // 8388608
  float*          gbias = (float*)(ws + 205520896);              // 16384
  unsigned short* hstep = (unsigned short*)(ws + 134217728);     // 33685504 (overlays Xbf + head of WxGb)

  // converts
  k_conv_bf16<<<16384, 256, 0, stream>>>(x, Xbf);
  k_conv_bf16<<<4096, 256, 0, stream>>>(Wx_g, WxGb);
  k_conv_bf16<<<4096, 256, 0, stream>>>(Wh_g, WhGb);
  k_transpose<<<dim3(32, 32), 256, 0, stream>>>(W_in, WinT, 1024, 1024);
  k_transpose<<<dim3(32, 32), 256, 0, stream>>>(W_hid, WhidT, 1024, 1024);
  // combined weights: Wxc = WxG @ W_in (via W_in^T), Whc = WhG @ W_hid
  k_gemm_bt<0><<<dim3(8, 32), 256, 0, stream>>>(WxGb, WinT, Wxc, nullptr, 4096, 1024, 1024);
  k_gemm_bt<0><<<dim3(8, 32), 256, 0, stream>>>(WhGb, WhidT, Whc, nullptr, 4096, 1024, 1024);
  k_bias<<<64, 256, 0, stream>>>(Wx_g, bx_g, b_in, Wh_g, bh_g, b_hid, gbias);
  // GX2 = tiled(X @ Wxc^T + gbias)  (fp16, per-(t,block) 8KB chunks)
  k_gemm_bt<1><<<dim3(32, 128), 256, 0, stream>>>(Xbf, Wxc, GX2, gbias, 16384, 4096, 1024);
  // poison the 257-slot h exchange buffer (overlays Xbf/WxGb head — both freed)
  hipMemsetAsync(hstep, 0xFF, 33685504, stream);
  // h0 into slot 0 (overwrites poison there)
  k_h0t<<<64, 256, 0, stream>>>(hidden, hstep);
  // sequential scan — no flags, no tags
  k_lstm_seq<<<SEQ_BLOCKS, 256, 0, stream>>>(GX2, Whc, cell, hstep, out);
}

// Round 10
// 2284.828 us; speedup vs baseline: 1.0410x; 1.0410x over previous
//
#include <hip/hip_runtime.h>

typedef __attribute__((ext_vector_type(8))) short short8;
typedef __attribute__((ext_vector_type(4))) float f32x4;

#define SEQ_BLOCKS 64
#define HEAT_BLOCKS 192

__device__ __forceinline__ unsigned short f2bf(float f) {
  unsigned u = __float_as_uint(f);
  u = u + 0x7fffu + ((u >> 16) & 1u);
  return (unsigned short)(u >> 16);
}
__device__ __forceinline__ unsigned short f2h(float f) {
  _Float16 h = (_Float16)f;
  unsigned short r;
  __builtin_memcpy(&r, &h, 2);
  return r;
}
__device__ __forceinline__ float h2f(unsigned short u) {
  _Float16 h;
  __builtin_memcpy(&h, &u, 2);
  return (float)h;
}
__device__ __forceinline__ void gload16(const void* g, void* l) {
  __builtin_amdgcn_global_load_lds(
      (const __attribute__((address_space(1))) unsigned int*)g,
      (__attribute__((address_space(3))) unsigned int*)l, 16, 0, 0);
}
__device__ __forceinline__ float fast_sigmoid(float x) {
  return 1.0f / (1.0f + __expf(-x));
}
__device__ __forceinline__ float fast_tanh(float x) {
  return 2.0f / (1.0f + __expf(-2.0f * x)) - 1.0f;
}
// L2-bypassing (sc0 sc1) atomics for cross-XCD exchange through L3
__device__ __forceinline__ unsigned long long ld_u64(const unsigned long long* p) {
  return __hip_atomic_load(p, __ATOMIC_RELAXED, __HIP_MEMORY_SCOPE_AGENT);
}
__device__ __forceinline__ short8 load_h16(const unsigned short* p) {
  union { unsigned long long u[2]; short8 s; } r;
  r.u[0] = ld_u64((const unsigned long long*)p);
  r.u[1] = ld_u64(((const unsigned long long*)p) + 1);
  return r.s;
}

// ---------- elementwise fp32 -> bf16 convert (vectorized) ----------
__global__ void k_conv_bf16(const float* __restrict__ in, unsigned short* __restrict__ out) {
  size_t i = ((size_t)blockIdx.x * 256 + threadIdx.x) * 4;
  float4 v = *(const float4*)(in + i);
  unsigned short o[4] = {f2bf(v.x), f2bf(v.y), f2bf(v.z), f2bf(v.w)};
  *(uint2*)(out + i) = *(const uint2*)o;
}

// ---------- h0 into transposed hT[0][sb][row][16] ----------
__global__ void k_h0t(const float* __restrict__ hidden, unsigned short* __restrict__ hT) {
  int sb = blockIdx.x;
  int row = threadIdx.x >> 2, c4 = (threadIdx.x & 3) * 4;
  float4 v = *(const float4*)(hidden + (size_t)row * 1024 + sb * 16 + c4);
  unsigned short o[4] = {f2bf(v.x), f2bf(v.y), f2bf(v.z), f2bf(v.w)};
  unsigned long long u;
  __builtin_memcpy(&u, o, 8);
  *(unsigned long long*)(hT + (size_t)sb * 1024 + row * 16 + c4) = u;
}

// ---------- transpose + convert: out[c][r] = bf16(in[r][c]) ----------
__global__ void k_transpose(const float* __restrict__ in, unsigned short* __restrict__ out,
                            int R, int C) {
  __shared__ float tile[32][33];
  int bx = blockIdx.x * 32, by = blockIdx.y * 32;
  int tx = threadIdx.x & 31, ty = threadIdx.x >> 5;  // ty 0..7
  for (int i = 0; i < 32; i += 8)
    tile[ty + i][tx] = in[(size_t)(by + ty + i) * C + bx + tx];
  __syncthreads();
  for (int i = 0; i < 32; i += 8)
    out[(size_t)(bx + ty + i) * R + by + tx] = f2bf(tile[tx][ty + i]);
}

// ---------- generic bf16 GEMM, C = A @ B^T (+bias), A[M][K], B[N][K] bf16 ----------
// OUTMODE 0: bf16 linear C[row][col]
// OUTMODE 1: fp16 tiled GX2[t][blk][g][b][jj]  (row = t*64+b, col = g*1024 + blk*16 + jj)
template<int OUTMODE>
__global__ __launch_bounds__(256) void k_gemm_bt(
    const unsigned short* __restrict__ A, const unsigned short* __restrict__ B,
    unsigned short* __restrict__ C, const float* __restrict__ bias,
    int M, int N, int K) {
  __shared__ unsigned short As[128 * 32];
  __shared__ unsigned short Bs[128 * 32];
  const int tid = threadIdx.x;
  const int wv = tid >> 6, l = tid & 63;
  const int m0 = blockIdx.y * 128, n0 = blockIdx.x * 128;
  const int wr = (wv >> 1) * 64, wc = (wv & 1) * 64;
  f32x4 acc[4][4] = {};
  for (int k0 = 0; k0 < K; k0 += 32) {
#pragma unroll
    for (int j = 0; j < 2; ++j) {
      int c = wv * 128 + j * 64 + l;
      int row = c >> 2, kc = (c & 3) * 8;
      gload16(A + (size_t)(m0 + row) * K + k0 + kc, (char*)As + c * 16);
      gload16(B + (size_t)(n0 + row) * K + k0 + kc, (char*)Bs + c * 16);
    }
    __syncthreads();
    short8 af[4], bfr[4];
#pragma unroll
    for (int rf = 0; rf < 4; ++rf)
      af[rf] = *(const short8*)(As + (wr + rf * 16 + (l & 15)) * 32 + (l >> 4) * 8);
#pragma unroll
    for (int cf = 0; cf < 4; ++cf)
      bfr[cf] = *(const short8*)(Bs + (wc + cf * 16 + (l & 15)) * 32 + (l >> 4) * 8);
#pragma unroll
    for (int rf = 0; rf < 4; ++rf)
#pragma unroll
      for (int cf = 0; cf < 4; ++cf)
        acc[rf][cf] = __builtin_amdgcn_mfma_f32_16x16x32_bf16(af[rf], bfr[cf], acc[rf][cf], 0, 0, 0);
    __syncthreads();
  }
#pragma unroll
  for (int cf = 0; cf < 4; ++cf) {
    int col = n0 + wc + cf * 16 + (l & 15);
    float bv = bias ? bias[col] : 0.0f;
#pragma unroll
    for (int rf = 0; rf < 4; ++rf) {
#pragma unroll
      for (int i = 0; i < 4; ++i) {
        int row = m0 + wr + rf * 16 + (l >> 4) * 4 + i;
        float v = acc[rf][cf][i] + bv;
        if (OUTMODE == 0) {
          C[(size_t)row * N + col] = f2bf(v);
        } else {
          int t = row >> 6, b = row & 63;
          int g = col >> 10, c = col & 1023;
          size_t idx = (size_t)(t * 64 + (c >> 4)) * 4096 + (g * 64 + b) * 16 + (c & 15);
          C[idx] = f2h(v);
        }
      }
    }
  }
}

// ---------- combined bias ----------
__global__ void k_bias(const float* __restrict__ Wxg, const float* __restrict__ bxg,
                       const float* __restrict__ b_in, const float* __restrict__ Whg,
                       const float* __restrict__ bhg, const float* __restrict__ b_hid,
                       float* __restrict__ gbias) {
  int col = blockIdx.x * 64 + (threadIdx.x >> 2);
  int p = threadIdx.x & 3;
  const float* wx = Wxg + (size_t)col * 1024;
  const float* wh = Whg + (size_t)col * 1024;
  float s = 0.f;
  for (int k = p * 256; k < p * 256 + 256; ++k)
    s += wx[k] * b_in[k] + wh[k] * b_hid[k];
  s += __shfl_down(s, 2, 4);
  s += __shfl_down(s, 1, 4);
  if (p == 0) gbias[col] = s + bxg[col] + bhg[col];
}

// ---------- persistent sequential LSTM scan + fabric heaters ----------
// Blocks 0..63: byte-identical R8 scan (best measured). Blocks 64..255:
// heaters — stream L2-bypassing reads of GX2 from L3 (~1.5 TB/s aggregate)
// until the scan's done-flag fires. Purpose: keep core+fabric clocks out of
// the idle-throttle regime that (theory) inflates every cross-die RTT ~4x.
// Heaters read via sc0/sc1 so they do NOT pollute any L2 the scan uses.
__global__ __launch_bounds__(256, 1) void k_lstm_fused(
    const unsigned short* __restrict__ GX2,  // fp16 tiled [256][64][4][64][16]
    const unsigned short* __restrict__ Whc,  // bf16 [4096][1024]
    const float* __restrict__ cell,          // [64][1024] f32
    unsigned short* __restrict__ hT,         // bf16 [4][64][64][16]
    float* __restrict__ out,                 // h [64][1024], c [64][1024] f32
    unsigned* __restrict__ flags) {          // [0..127]=tags, [192]=done
  __shared__ float pbuf[34816];              // 139 KB (forces 1 block/CU spread)
  const int tid = threadIdx.x;

  if (blockIdx.x >= SEQ_BLOCKS) {
    // ---------------- heater role ----------------
    const int w = blockIdx.x - SEQ_BLOCKS;
    const unsigned long long* base =
        (const unsigned long long*)GX2 + (size_t)w * 65536;  // 512KB slice
    const unsigned* done = flags + 192;
    unsigned long long acc = 0;
    unsigned off = tid * 2;
    for (;;) {
      if (__hip_atomic_load(done, __ATOMIC_RELAXED, __HIP_MEMORY_SCOPE_AGENT)) break;
#pragma unroll
      for (int i = 0; i < 4; ++i)
        acc ^= ld_u64(base + ((off + i * 512) & 65535));
      off += 2048;
      __builtin_amdgcn_s_sleep(15);
      __builtin_amdgcn_s_sleep(15);
    }
    asm volatile("" :: "v"((unsigned)acc), "v"((unsigned)(acc >> 32)));
    return;
  }

  // ---------------- scan role (R8, unchanged) ----------------
  const int wv = tid >> 6, l = tid & 63;
  const int bid = blockIdx.x;
  const int a = l & 15, q = l >> 4;

  short8 w[4][8];
#pragma unroll
  for (int ct = 0; ct < 4; ++ct)
#pragma unroll
    for (int u = 0; u < 8; ++u)
      w[ct][u] = *(const short8*)(
          Whc + (size_t)(ct * 1024 + bid * 16 + a) * 1024 + wv * 256 + u * 32 + q * 8);

  const int eb = tid >> 2;
  const int ej = (tid & 3) * 4;
  float c_reg[4];
  {
    float4 c4 = *(const float4*)(cell + (size_t)eb * 1024 + bid * 16 + ej);
    c_reg[0] = c4.x; c_reg[1] = c4.y; c_reg[2] = c4.z; c_reg[3] = c4.w;
  }

  const size_t abase = (size_t)(wv * 16 + (q >> 1)) * 1024 + a * 16 + (q & 1) * 8;
  const unsigned* pollp = flags + wv * 32 + a;

  for (int t = 0; t < 256; ++t) {
    const unsigned short* chunk = GX2 + ((size_t)t * 64 + bid) * 4096;
    unsigned long long gxu[4];
#pragma unroll
    for (int g = 0; g < 4; ++g)
      gxu[g] = *(const unsigned long long*)(chunk + (g * 64 + eb) * 16 + ej);

    if (t > 0) {
      const unsigned tgt = (unsigned)t;
      for (;;) {
        unsigned v = __hip_atomic_load(pollp, __ATOMIC_RELAXED, __HIP_MEMORY_SCOPE_AGENT);
        if (__all((int)(v >= tgt))) break;
        __builtin_amdgcn_s_sleep(1);
      }
      __builtin_amdgcn_fence(__ATOMIC_ACQUIRE, "workgroup");
    }

    const unsigned short* hb = hT + ((size_t)(t & 3) << 16) + abase;
    short8 afr[4][8];
#pragma unroll
    for (int u = 0; u < 8; ++u)
#pragma unroll
      for (int rt = 0; rt < 4; ++rt)
        afr[rt][u] = load_h16(hb + u * 2048 + rt * 256);

    f32x4 acc[4][4] = {};
#pragma unroll
    for (int u = 0; u < 8; ++u)
#pragma unroll
      for (int rt = 0; rt < 4; ++rt)
#pragma unroll
        for (int ct = 0; ct < 4; ++ct)
          acc[rt][ct] = __builtin_amdgcn_mfma_f32_16x16x32_bf16(afr[rt][u], w[ct][u],
                                                                acc[rt][ct], 0, 0, 0);

    const int pb = (t & 1) * 17408 + wv * 4352;
#pragma unroll
    for (int rt = 0; rt < 4; ++rt)
#pragma unroll
      for (int ct = 0; ct < 4; ++ct) {
        int gc = a * 4 + ct;
        int b0 = (rt * 16 + q * 4) ^ ((((gc) >> 3) & 3) << 2);
        *(f32x4*)&pbuf[pb + gc * 68 + b0] = acc[rt][ct];
      }
    __syncthreads();

    const int pr = (t & 1) * 17408;
    float sg[4][4];
#pragma unroll
    for (int g = 0; g < 4; ++g) {
      unsigned short gx4[4];
      __builtin_memcpy(gx4, &gxu[g], 8);
#pragma unroll
      for (int i = 0; i < 4; ++i) {
        int gc = (ej + i) * 4 + g;
        int bx = eb ^ ((((gc) >> 3) & 3) << 2);
        float s = pbuf[pr + 0 * 4352 + gc * 68 + bx] + pbuf[pr + 1 * 4352 + gc * 68 + bx] +
                  pbuf[pr + 2 * 4352 + gc * 68 + bx] + pbuf[pr + 3 * 4352 + gc * 68 + bx];
        sg[g][i] = s + h2f(gx4[i]);
      }
    }
    float hnew[4];
#pragma unroll
    for (int i = 0; i < 4; ++i) {
      float ig = fast_sigmoid(sg[0][i]);
      float fg = fast_sigmoid(sg[1][i]);
      float gg = fast_tanh(sg[2][i]);
      float og = fast_sigmoid(sg[3][i]);
      c_reg[i] = fg * c_reg[i] + ig * gg;
      hnew[i] = og * fast_tanh(c_reg[i]);
    }

    if (t == 255) {
      float4 h4 = {hnew[0], hnew[1], hnew[2], hnew[3]};
      float4 c4 = {c_reg[0], c_reg[1], c_reg[2], c_reg[3]};
      *(float4*)(out + (size_t)eb * 1024 + bid * 16 + ej) = h4;
      *(float4*)(out + 65536 + (size_t)eb * 1024 + bid * 16 + ej) = c4;
    } else {
      unsigned short hs[4] = {f2bf(hnew[0]), f2bf(hnew[1]), f2bf(hnew[2]), f2bf(hnew[3])};
      unsigned long long hv;
      __builtin_memcpy(&hv, hs, 8);
      __hip_atomic_store(
          (unsigned long long*)(hT + ((size_t)((t + 1) & 3) << 16) + (size_t)bid * 1024 +
                                eb * 16 + ej),
          hv, __ATOMIC_RELAXED, __HIP_MEMORY_SCOPE_AGENT);
      asm volatile("s_waitcnt vmcnt(0)" ::: "memory");
      __syncthreads();
      if (tid == 0)
        __hip_atomic_store(&flags[(bid >> 4) * 32 + (bid & 15)], (unsigned)(t + 1),
                           __ATOMIC_RELAXED, __HIP_MEMORY_SCOPE_AGENT);
    }
  }

  if (bid == 0 && tid == 0)
    __hip_atomic_store(flags + 192, 1u, __ATOMIC_RELAXED, __HIP_MEMORY_SCOPE_AGENT);
}

extern "C" void kernel_launch(void* const* d_in, const int* in_sizes, int n_in,
                              void* d_out, int out_size, void* d_ws, size_t ws_size,
                              hipStream_t stream) {
  const float* x      = (const float*)d_in[0];
  const float* hidden = (const float*)d_in[1];
  const float* cell   = (const float*)d_in[2];
  const float* W_in   = (const float*)d_in[3];
  const float* b_in   = (const float*)d_in[4];
  const float* W_hid  = (const float*)d_in[5];
  const float* b_hid  = (const float*)d_in[6];
  const float* Wx_g   = (const float*)d_in[7];
  const float* bx_g   = (const float*)d_in[8];
  const float* Wh_g   = (const float*)d_in[9];
  const float* bh_g   = (const float*)d_in[10];
  float* out = (float*)d_out;

  char* ws = (char*)d_ws;
  unsigned short* GX2   = (unsigned short*)(ws);                 // 134217728 B (fp16 tiled)
  unsigned short* Xbf   = (unsigned short*)(ws + 134217728);     // 33554432 (freed after GX gemm)
  unsigned short* WxGb  = (unsigned short*)(ws + 167772160);     // 8388608
  unsigned short* WhGb  = (unsigned short*)(ws + 176160768);     // 8388608
  unsigned short* WinT  = (unsigned short*)(ws + 184549376);     // 2097152 (reused for flags)
  unsigned short* WhidT = (unsigned short*)(ws + 186646528);     // 2097152
  unsigned short* Wxc   = (unsigned short*)(ws + 188743680);     // 8388608
  unsigned short* Whc   = (unsigned short*)(ws + 197132288);     // 8388608
  float*          gbias = (float*)(ws + 205520896);              // 16384
  unsigned short* hT    = (unsigned short*)(ws + 134217728);     // 1 MB (overlays Xbf)
  unsigned*       flags = (unsigned*)(ws + 184549376);           // 1 KB (overlays WinT)

  // converts
  k_conv_bf16<<<16384, 256, 0, stream>>>(x, Xbf);
  k_conv_bf16<<<4096, 256, 0, stream>>>(Wx_g, WxGb);
  k_conv_bf16<<<4096, 256, 0, stream>>>(Wh_g, WhGb);
  k_transpose<<<dim3(32, 32), 256, 0, stream>>>(W_in, WinT, 1024, 1024);
  k_transpose<<<dim3(32, 32), 256, 0, stream>>>(W_hid, WhidT, 1024, 1024);
  // combined weights: Wxc = WxG @ W_in (via W_in^T), Whc = WhG @ W_hid
  k_gemm_bt<0><<<dim3(8, 32), 256, 0, stream>>>(WxGb, WinT, Wxc, nullptr, 4096, 1024, 1024);
  k_gemm_bt<0><<<dim3(8, 32), 256, 0, stream>>>(WhGb, WhidT, Whc, nullptr, 4096, 1024, 1024);
  k_bias<<<64, 256, 0, stream>>>(Wx_g, bx_g, b_in, Wh_g, bh_g, b_hid, gbias);
  // GX2 = tiled(X @ Wxc^T + gbias)  (fp16, per-(t,block) 8KB chunks)
  k_gemm_bt<1><<<dim3(32, 128), 256, 0, stream>>>(Xbf, Wxc, GX2, gbias, 16384, 4096, 1024);
  // h0 into hT[0] (overlays Xbf — all Xbf consumers done above)
  k_h0t<<<64, 256, 0, stream>>>(hidden, hT);
  // tag lines + done flag
  hipMemsetAsync(flags, 0, 1024, stream);
  // scan (64 blocks) + fabric heaters (192 blocks)
  k_lstm_fused<<<SEQ_BLOCKS + HEAT_BLOCKS, 256, 0, stream>>>(GX2, Whc, cell, hT, out, flags);
}

// Round 11
// 2165.752 us; speedup vs baseline: 1.0982x; 1.0550x over previous
//
#include <hip/hip_runtime.h>

typedef __attribute__((ext_vector_type(8))) short short8;
typedef __attribute__((ext_vector_type(4))) float f32x4;

#define SEQ_BLOCKS 64

__device__ __forceinline__ unsigned short f2bf(float f) {
  unsigned u = __float_as_uint(f);
  u = u + 0x7fffu + ((u >> 16) & 1u);
  return (unsigned short)(u >> 16);
}
__device__ __forceinline__ unsigned short f2h(float f) {
  _Float16 h = (_Float16)f;
  unsigned short r;
  __builtin_memcpy(&r, &h, 2);
  return r;
}
__device__ __forceinline__ float h2f(unsigned short u) {
  _Float16 h;
  __builtin_memcpy(&h, &u, 2);
  return (float)h;
}
__device__ __forceinline__ void gload16(const void* g, void* l) {
  __builtin_amdgcn_global_load_lds(
      (const __attribute__((address_space(1))) unsigned int*)g,
      (__attribute__((address_space(3))) unsigned int*)l, 16, 0, 0);
}
__device__ __forceinline__ float fast_sigmoid(float x) {
  return 1.0f / (1.0f + __expf(-x));
}
__device__ __forceinline__ float fast_tanh(float x) {
  return 2.0f / (1.0f + __expf(-2.0f * x)) - 1.0f;
}

// ---------- elementwise fp32 -> bf16 convert (vectorized) ----------
__global__ void k_conv_bf16(const float* __restrict__ in, unsigned short* __restrict__ out) {
  size_t i = ((size_t)blockIdx.x * 256 + threadIdx.x) * 4;
  float4 v = *(const float4*)(in + i);
  unsigned short o[4] = {f2bf(v.x), f2bf(v.y), f2bf(v.z), f2bf(v.w)};
  *(uint2*)(out + i) = *(const uint2*)o;
}

// ---------- h0 into slot 0: hstep[0][sb][row][16] ----------
__global__ void k_h0t(const float* __restrict__ hidden, unsigned short* __restrict__ hT) {
  int sb = blockIdx.x;
  int row = threadIdx.x >> 2, c4 = (threadIdx.x & 3) * 4;
  float4 v = *(const float4*)(hidden + (size_t)row * 1024 + sb * 16 + c4);
  unsigned short o[4] = {f2bf(v.x), f2bf(v.y), f2bf(v.z), f2bf(v.w)};
  unsigned long long u;
  __builtin_memcpy(&u, o, 8);
  *(unsigned long long*)(hT + (size_t)sb * 1024 + row * 16 + c4) = u;
}

// ---------- transpose + convert: out[c][r] = bf16(in[r][c]) ----------
__global__ void k_transpose(const float* __restrict__ in, unsigned short* __restrict__ out,
                            int R, int C) {
  __shared__ float tile[32][33];
  int bx = blockIdx.x * 32, by = blockIdx.y * 32;
  int tx = threadIdx.x & 31, ty = threadIdx.x >> 5;  // ty 0..7
  for (int i = 0; i < 32; i += 8)
    tile[ty + i][tx] = in[(size_t)(by + ty + i) * C + bx + tx];
  __syncthreads();
  for (int i = 0; i < 32; i += 8)
    out[(size_t)(bx + ty + i) * R + by + tx] = f2bf(tile[tx][ty + i]);
}

// ---------- generic bf16 GEMM, C = A @ B^T (+bias), A[M][K], B[N][K] bf16 ----------
// OUTMODE 0: bf16 linear C[row][col]
// OUTMODE 1: fp16 tiled GX2[t][blk][g][b][jj]  (row = t*64+b, col = g*1024 + blk*16 + jj)
template<int OUTMODE>
__global__ __launch_bounds__(256) void k_gemm_bt(
    const unsigned short* __restrict__ A, const unsigned short* __restrict__ B,
    unsigned short* __restrict__ C, const float* __restrict__ bias,
    int M, int N, int K) {
  __shared__ unsigned short As[128 * 32];
  __shared__ unsigned short Bs[128 * 32];
  const int tid = threadIdx.x;
  const int wv = tid >> 6, l = tid & 63;
  const int m0 = blockIdx.y * 128, n0 = blockIdx.x * 128;
  const int wr = (wv >> 1) * 64, wc = (wv & 1) * 64;
  f32x4 acc[4][4] = {};
  for (int k0 = 0; k0 < K; k0 += 32) {
#pragma unroll
    for (int j = 0; j < 2; ++j) {
      int c = wv * 128 + j * 64 + l;
      int row = c >> 2, kc = (c & 3) * 8;
      gload16(A + (size_t)(m0 + row) * K + k0 + kc, (char*)As + c * 16);
      gload16(B + (size_t)(n0 + row) * K + k0 + kc, (char*)Bs + c * 16);
    }
    __syncthreads();
    short8 af[4], bfr[4];
#pragma unroll
    for (int rf = 0; rf < 4; ++rf)
      af[rf] = *(const short8*)(As + (wr + rf * 16 + (l & 15)) * 32 + (l >> 4) * 8);
#pragma unroll
    for (int cf = 0; cf < 4; ++cf)
      bfr[cf] = *(const short8*)(Bs + (wc + cf * 16 + (l & 15)) * 32 + (l >> 4) * 8);
#pragma unroll
    for (int rf = 0; rf < 4; ++rf)
#pragma unroll
      for (int cf = 0; cf < 4; ++cf)
        acc[rf][cf] = __builtin_amdgcn_mfma_f32_16x16x32_bf16(af[rf], bfr[cf], acc[rf][cf], 0, 0, 0);
    __syncthreads();
  }
#pragma unroll
  for (int cf = 0; cf < 4; ++cf) {
    int col = n0 + wc + cf * 16 + (l & 15);
    float bv = bias ? bias[col] : 0.0f;
#pragma unroll
    for (int rf = 0; rf < 4; ++rf) {
#pragma unroll
      for (int i = 0; i < 4; ++i) {
        int row = m0 + wr + rf * 16 + (l >> 4) * 4 + i;
        float v = acc[rf][cf][i] + bv;
        if (OUTMODE == 0) {
          C[(size_t)row * N + col] = f2bf(v);
        } else {
          int t = row >> 6, b = row & 63;
          int g = col >> 10, c = col & 1023;
          size_t idx = (size_t)(t * 64 + (c >> 4)) * 4096 + (g * 64 + b) * 16 + (c & 15);
          C[idx] = f2h(v);
        }
      }
    }
  }
}

// ---------- combined bias ----------
__global__ void k_bias(const float* __restrict__ Wxg, const float* __restrict__ bxg,
                       const float* __restrict__ b_in, const float* __restrict__ Whg,
                       const float* __restrict__ bhg, const float* __restrict__ b_hid,
                       float* __restrict__ gbias) {
  int col = blockIdx.x * 64 + (threadIdx.x >> 2);
  int p = threadIdx.x & 3;
  const float* wx = Wxg + (size_t)col * 1024;
  const float* wh = Whg + (size_t)col * 1024;
  float s = 0.f;
  for (int k = p * 256; k < p * 256 + 256; ++k)
    s += wx[k] * b_in[k] + wh[k] * b_hid[k];
  s += __shfl_down(s, 2, 4);
  s += __shfl_down(s, 1, 4);
  if (p == 0) gbias[col] = s + bxg[col] + bhg[col];
}

// ---------- persistent sequential LSTM scan ----------
// R8 protocol, with DEPTH-256 h buffer + CACHED consumer loads:
//  - hstep[257 slots][64 src][64 row][16 col]: every step writes a fresh,
//    never-before-read address -> consumer L2 can't hold a stale copy ->
//    consumers use NORMAL cached loads. 8 blocks per XCD share each h line
//    via their L2 (8x less L3 traffic; 7/8 of A-reads become L2 hits).
//  - producers keep sc0/sc1 u64 stores (straight to L3, no wbl2/inv),
//    vmcnt(0) + barrier + one packed tag; consumer polls ONE tag line/wave.
__global__ __launch_bounds__(256, 1) void k_lstm_seq(
    const unsigned short* __restrict__ GX2,  // fp16 tiled [256][64][4][64][16]
    const unsigned short* __restrict__ Whc,  // bf16 [4096][1024]
    const float* __restrict__ cell,          // [64][1024] f32
    unsigned short* __restrict__ hstep,      // bf16 [257][64][64][16]
    float* __restrict__ out,                 // h [64][1024], c [64][1024] f32
    unsigned* __restrict__ flags) {          // [4 groups][32 u32]: 16 tags/line
  __shared__ float pbuf[34816];              // 139 KB: (t&1)*17408 + s*4352 + gc*68 + b
  const int tid = threadIdx.x;
  const int wv = tid >> 6, l = tid & 63;
  const int bid = blockIdx.x;
  const int a = l & 15, q = l >> 4;

  // ---- weights: w[ct][u] = gate ct, h-col a of block; k = wv*256+u*32+q*8 ----
  short8 w[4][8];
#pragma unroll
  for (int ct = 0; ct < 4; ++ct)
#pragma unroll
    for (int u = 0; u < 8; ++u)
      w[ct][u] = *(const short8*)(
          Whc + (size_t)(ct * 1024 + bid * 16 + a) * 1024 + wv * 256 + u * 32 + q * 8);

  // elementwise ownership: batch-row eb, h-cols ej..ej+3
  const int eb = tid >> 2;
  const int ej = (tid & 3) * 4;
  float c_reg[4];
  {
    float4 c4 = *(const float4*)(cell + (size_t)eb * 1024 + bid * 16 + ej);
    c_reg[0] = c4.x; c_reg[1] = c4.y; c_reg[2] = c4.z; c_reg[3] = c4.w;
  }

  // A-load base inside a slot: src = wv*16 + 2u + (q>>1), row a, col8 = (q&1)*8
  const size_t abase = (size_t)(wv * 16 + (q >> 1)) * 1024 + a * 16 + (q & 1) * 8;
  // poll: wave wv's 16 sources' tags all live in line wv
  const unsigned* pollp = flags + wv * 32 + a;

  for (int t = 0; t < 256; ++t) {
    // --- GX prefetch (plain loads; complete under the poll) ---
    const unsigned short* chunk = GX2 + ((size_t)t * 64 + bid) * 4096;
    unsigned long long gxu[4];
#pragma unroll
    for (int g = 0; g < 4; ++g)
      gxu[g] = *(const unsigned long long*)(chunk + (g * 64 + eb) * 16 + ej);

    // --- wait for the 16 source-block tags (ONE line per wave) ---
    if (t > 0) {
      const unsigned tgt = (unsigned)t;
      for (;;) {
        unsigned v = __hip_atomic_load(pollp, __ATOMIC_RELAXED, __HIP_MEMORY_SCOPE_AGENT);
        if (__all((int)(v >= tgt))) break;
        __builtin_amdgcn_s_sleep(1);
      }
      __builtin_amdgcn_fence(__ATOMIC_ACQUIRE, "workgroup");
      __builtin_amdgcn_sched_barrier(0);
    }

    // --- load A from slot t with NORMAL cached loads (fresh addresses) ---
    const unsigned short* hb = hstep + ((size_t)t << 16) + abase;
    short8 afr[4][8];
#pragma unroll
    for (int u = 0; u < 8; ++u)
#pragma unroll
      for (int rt = 0; rt < 4; ++rt)
        afr[rt][u] = *(const short8*)(hb + u * 2048 + rt * 256);

    // --- 128 MFMA, all operands in registers ---
    f32x4 acc[4][4] = {};
#pragma unroll
    for (int u = 0; u < 8; ++u)
#pragma unroll
      for (int rt = 0; rt < 4; ++rt)
#pragma unroll
        for (int ct = 0; ct < 4; ++ct)
          acc[rt][ct] = __builtin_amdgcn_mfma_f32_16x16x32_bf16(afr[rt][u], w[ct][u],
                                                                acc[rt][ct], 0, 0, 0);

    // --- partials to LDS (0-conflict layout): f32x4 over batch ---
    const int pb = (t & 1) * 17408 + wv * 4352;
#pragma unroll
    for (int rt = 0; rt < 4; ++rt)
#pragma unroll
      for (int ct = 0; ct < 4; ++ct) {
        int gc = a * 4 + ct;                              // h-col-major gate-col
        int b0 = (rt * 16 + q * 4) ^ ((((gc) >> 3) & 3) << 2);
        *(f32x4*)&pbuf[pb + gc * 68 + b0] = acc[rt][ct];
      }
    __syncthreads();

    // --- reduce 4 k-slots + GX, gates for (row eb, cols ej..ej+3) ---
    const int pr = (t & 1) * 17408;
    float sg[4][4];
#pragma unroll
    for (int g = 0; g < 4; ++g) {
      unsigned short gx4[4];
      __builtin_memcpy(gx4, &gxu[g], 8);
#pragma unroll
      for (int i = 0; i < 4; ++i) {
        int gc = (ej + i) * 4 + g;
        int bx = eb ^ ((((gc) >> 3) & 3) << 2);
        float s = pbuf[pr + 0 * 4352 + gc * 68 + bx] + pbuf[pr + 1 * 4352 + gc * 68 + bx] +
                  pbuf[pr + 2 * 4352 + gc * 68 + bx] + pbuf[pr + 3 * 4352 + gc * 68 + bx];
        sg[g][i] = s + h2f(gx4[i]);
      }
    }
    float hnew[4];
#pragma unroll
    for (int i = 0; i < 4; ++i) {
      float ig = fast_sigmoid(sg[0][i]);
      float fg = fast_sigmoid(sg[1][i]);
      float gg = fast_tanh(sg[2][i]);
      float og = fast_sigmoid(sg[3][i]);
      c_reg[i] = fg * c_reg[i] + ig * gg;
      hnew[i] = og * fast_tanh(c_reg[i]);
    }

    if (t == 255) {
      float4 h4 = {hnew[0], hnew[1], hnew[2], hnew[3]};
      float4 c4 = {c_reg[0], c_reg[1], c_reg[2], c_reg[3]};
      *(float4*)(out + (size_t)eb * 1024 + bid * 16 + ej) = h4;
      *(float4*)(out + 65536 + (size_t)eb * 1024 + bid * 16 + ej) = c4;
    } else {
      // h(t+1) into FRESH slot t+1 (u64 packed sc0/sc1 stores -> L3)
      unsigned short hs[4] = {f2bf(hnew[0]), f2bf(hnew[1]), f2bf(hnew[2]), f2bf(hnew[3])};
      unsigned long long hv;
      __builtin_memcpy(&hv, hs, 8);
      __hip_atomic_store(
          (unsigned long long*)(hstep + ((size_t)(t + 1) << 16) + (size_t)bid * 1024 +
                                eb * 16 + ej),
          hv, __ATOMIC_RELAXED, __HIP_MEMORY_SCOPE_AGENT);
      asm volatile("s_waitcnt vmcnt(0)" ::: "memory");  // this wave's stores at L3
      __syncthreads();                                   // all 4 waves' stores done
      if (tid == 0)
        __hip_atomic_store(&flags[(bid >> 4) * 32 + (bid & 15)], (unsigned)(t + 1),
                           __ATOMIC_RELAXED, __HIP_MEMORY_SCOPE_AGENT);
    }
  }
}

extern "C" void kernel_launch(void* const* d_in, const int* in_sizes, int n_in,
                              void* d_out, int out_size, void* d_ws, size_t ws_size,
                              hipStream_t stream) {
  const float* x      = (const float*)d_in[0];
  const float* hidden = (const float*)d_in[1];
  const float* cell   = (const float*)d_in[2];
  const float* W_in   = (const float*)d_in[3];
  const float* b_in   = (const float*)d_in[4];
  const float* W_hid  = (const float*)d_in[5];
  const float* b_hid  = (const float*)d_in[6];
  const float* Wx_g   = (const float*)d_in[7];
  const float* bx_g   = (const float*)d_in[8];
  const float* Wh_g   = (const float*)d_in[9];
  const float* bh_g   = (const float*)d_in[10];
  float* out = (float*)d_out;

  char* ws = (char*)d_ws;
  unsigned short* GX2   = (unsigned short*)(ws);                 // 134217728 B (fp16 tiled)
  unsigned short* Xbf   = (unsigned short*)(ws + 134217728);     // 33554432 (freed after GX gemm)
  unsigned short* WxGb  = (unsigned short*)(ws + 167772160);     // 8388608 (freed after Wxc gemm)
  unsigned short* WhGb  = (unsigned short*)(ws + 176160768);     // 8388608
  unsigned short* WinT  = (unsigned short*)(ws + 184549376);     // 2097152 (reused for flags)
  unsigned short* WhidT = (unsigned short*)(ws + 186646528);     // 2097152
  unsigned short* Wxc   = (unsigned short*)(ws + 188743680);     // 8388608
  unsigned short* Whc   = (unsigned short*)(ws + 197132288);     // 8388608
  float*          gbias = (float*)(ws + 205520896);              // 16384
  unsigned short* hstep = (unsigned short*)(ws + 134217728);     // 33685504 (overlays Xbf + WxGb head)
  unsigned*       flags = (unsigned*)(ws + 184549376);           // 512 B (overlays WinT)

  // converts
  k_conv_bf16<<<16384, 256, 0, stream>>>(x, Xbf);
  k_conv_bf16<<<4096, 256, 0, stream>>>(Wx_g, WxGb);
  k_conv_bf16<<<4096, 256, 0, stream>>>(Wh_g, WhGb);
  k_transpose<<<dim3(32, 32), 256, 0, stream>>>(W_in, WinT, 1024, 1024);
  k_transpose<<<dim3(32, 32), 256, 0, stream>>>(W_hid, WhidT, 1024, 1024);
  // combined weights: Wxc = WxG @ W_in (via W_in^T), Whc = WhG @ W_hid
  k_gemm_bt<0><<<dim3(8, 32), 256, 0, stream>>>(WxGb, WinT, Wxc, nullptr, 4096, 1024, 1024);
  k_gemm_bt<0><<<dim3(8, 32), 256, 0, stream>>>(WhGb, WhidT, Whc, nullptr, 4096, 1024, 1024);
  k_bias<<<64, 256, 0, stream>>>(Wx_g, bx_g, b_in, Wh_g, bh_g, b_hid, gbias);
  // GX2 = tiled(X @ Wxc^T + gbias)  (fp16, per-(t,block) 8KB chunks)
  k_gemm_bt<1><<<dim3(32, 128), 256, 0, stream>>>(Xbf, Wxc, GX2, gbias, 16384, 4096, 1024);
  // h0 into slot 0 (overlays Xbf — all Xbf consumers done above)
  k_h0t<<<64, 256, 0, stream>>>(hidden, hstep);
  // packed tag lines
  hipMemsetAsync(flags, 0, 512, stream);
  // sequential scan
  k_lstm_seq<<<SEQ_BLOCKS, 256, 0, stream>>>(GX2, Whc, cell, hstep, out, flags);
}